// Round 1
// baseline (86524.072 us; speedup 1.0000x reference)
//
#include <hip/hip_runtime.h>
#include <math.h>

// Problem constants
#define BB 64      // batch
#define TT 512     // time steps
#define II 64      // input dim (layer 0)
#define HH 512     // hidden dim
#define NB_PER_LAYER 64
#define HPB 8      // h-units per block
#define NBLK 192   // 3 layers * 64 blocks
#define NWAVES (TT + 2)

__device__ __forceinline__ float sigmoidf_(float x) {
    return 1.0f / (1.0f + expf(-x));
}

// Sense-reversal grid barrier. cnt at bar[0], gen at bar[16] (separate cachelines).
// Requires all blocks co-resident (grid=192 <= 256 CUs, modest VGPR/LDS).
__device__ __forceinline__ void grid_barrier(unsigned* bar, unsigned nblk) {
    __syncthreads();
    if (threadIdx.x == 0) {
        __threadfence();
        unsigned* cnt = bar;
        unsigned* gen = bar + 16;
        unsigned g = __hip_atomic_load(gen, __ATOMIC_RELAXED, __HIP_MEMORY_SCOPE_AGENT);
        unsigned arrived = __hip_atomic_fetch_add(cnt, 1u, __ATOMIC_ACQ_REL, __HIP_MEMORY_SCOPE_AGENT);
        if (arrived == nblk - 1) {
            __hip_atomic_store(cnt, 0u, __ATOMIC_RELAXED, __HIP_MEMORY_SCOPE_AGENT);
            __hip_atomic_fetch_add(gen, 1u, __ATOMIC_RELEASE, __HIP_MEMORY_SCOPE_AGENT);
        } else {
            while (__hip_atomic_load(gen, __ATOMIC_ACQUIRE, __HIP_MEMORY_SCOPE_AGENT) == g) {
                __builtin_amdgcn_s_sleep(2);
            }
        }
        __threadfence();
    }
    __syncthreads();
}

// x [B,T,I] -> xT [T][I][B] so that lane=batch reads are coalesced in the scan.
__global__ __launch_bounds__(256) void transpose_x_kernel(
    const float* __restrict__ x, float* __restrict__ xT) {
    __shared__ float tile[64][65];
    int t = blockIdx.x;
    int a = threadIdx.x & 63;   // load: i index / store: b index
    int q = threadIdx.x >> 6;   // 0..3
    #pragma unroll
    for (int r = 0; r < 16; ++r) {
        int bb = q * 16 + r;
        tile[a][bb] = x[((size_t)bb * TT + t) * II + a];  // coalesced over i
    }
    __syncthreads();
    #pragma unroll
    for (int r = 0; r < 16; ++r) {
        int ii = q * 16 + r;
        xT[((size_t)t * II + ii) * BB + a] = tile[ii][a]; // coalesced over b
    }
}

// Persistent layer-wavefront LSTM scan. Layer l = blockIdx.x/64 handles
// h-slice [tile*8, tile*8+8) for all 64 batch elements. Thread = (lane_b, 2 h-units).
// All 4 gates of a (b, h) pair live in one thread -> cell update is thread-local.
__global__ __launch_bounds__(256) void lstm_wavefront(
    const float* __restrict__ xT,
    float* __restrict__ trajA,   // layer0 output trajectory [T][H][B]
    float* __restrict__ trajB,   // layer1 output trajectory [T][H][B]
    float* __restrict__ cbuf,    // [3][H][B] cell state
    float* __restrict__ h2pp,    // [2][H][B] layer2 h ping-pong
    unsigned* __restrict__ bar,
    const float* __restrict__ Wih0, const float* __restrict__ Whh0,
    const float* __restrict__ bih0, const float* __restrict__ bhh0,
    const float* __restrict__ Wih1, const float* __restrict__ Whh1,
    const float* __restrict__ bih1, const float* __restrict__ bhh1,
    const float* __restrict__ Wih2, const float* __restrict__ Whh2,
    const float* __restrict__ bih2, const float* __restrict__ bhh2,
    const float* __restrict__ fcw, const float* __restrict__ fcb,
    float* __restrict__ out) {

    const int l = blockIdx.x >> 6;          // layer 0,1,2
    const int tile = blockIdx.x & 63;
    const int hbase = tile * HPB;
    const int lane_b = threadIdx.x & 63;    // batch index (lane)
    const int hq = threadIdx.x >> 6;        // 0..3
    const int hu0 = hbase + hq * 2;         // this thread's 2 h-units

    const float* Wih = (l == 0) ? Wih0 : ((l == 1) ? Wih1 : Wih2);
    const float* Whh = (l == 0) ? Whh0 : ((l == 1) ? Whh1 : Whh2);
    const float* bih = (l == 0) ? bih0 : ((l == 1) ? bih1 : bih2);
    const float* bhh = (l == 0) ? bhh0 : ((l == 1) ? bhh1 : bhh2);
    const int in_dim = (l == 0) ? II : HH;
    const float* xin_base = (l == 0) ? xT : ((l == 1) ? trajA : trajB);
    float* traj_out = (l == 0) ? trajA : ((l == 1) ? trajB : nullptr);

    // Hoist weight row pointers and biases. j = u*4 + g, row = g*H + hu0 + u.
    const float* Wih_r[8];
    const float* Whh_r[8];
    float bias[8];
    #pragma unroll
    for (int j = 0; j < 8; ++j) {
        int u = j >> 2;
        int g = j & 3;
        int row = g * HH + hu0 + u;
        Wih_r[j] = Wih + (size_t)row * in_dim;
        Whh_r[j] = Whh + (size_t)row * HH;
        bias[j] = bih[row] + bhh[row];
    }

    for (int w = 0; w < NWAVES; ++w) {
        const int t = w - l;
        if (t >= 0 && t < TT) {
            float acc[8];
            #pragma unroll
            for (int j = 0; j < 8; ++j) acc[j] = 0.0f;

            // ---- input projection: xin_t @ W_ih^T ----
            const float* xin = xin_base + (size_t)t * in_dim * BB;
            for (int k = 0; k < in_dim; k += 4) {
                float x0 = xin[(k + 0) * BB + lane_b];
                float x1 = xin[(k + 1) * BB + lane_b];
                float x2 = xin[(k + 2) * BB + lane_b];
                float x3 = xin[(k + 3) * BB + lane_b];
                #pragma unroll
                for (int j = 0; j < 8; ++j) {
                    float4 wv = *(const float4*)(Wih_r[j] + k);
                    acc[j] = fmaf(x3, wv.w, fmaf(x2, wv.z, fmaf(x1, wv.y, fmaf(x0, wv.x, acc[j]))));
                }
            }

            // ---- recurrent projection: h_{t-1} @ W_hh^T ----
            if (t > 0) {
                const float* hp = (l == 2)
                    ? (h2pp + (size_t)((t - 1) & 1) * HH * BB)
                    : (traj_out + (size_t)(t - 1) * HH * BB);
                for (int k = 0; k < HH; k += 4) {
                    float h0 = hp[(k + 0) * BB + lane_b];
                    float h1 = hp[(k + 1) * BB + lane_b];
                    float h2 = hp[(k + 2) * BB + lane_b];
                    float h3 = hp[(k + 3) * BB + lane_b];
                    #pragma unroll
                    for (int j = 0; j < 8; ++j) {
                        float4 wv = *(const float4*)(Whh_r[j] + k);
                        acc[j] = fmaf(h3, wv.w, fmaf(h2, wv.z, fmaf(h1, wv.y, fmaf(h0, wv.x, acc[j]))));
                    }
                }
            }

            // ---- LSTM cell update (thread-local: owns all 4 gates) ----
            #pragma unroll
            for (int u = 0; u < 2; ++u) {
                float iv = sigmoidf_(acc[u * 4 + 0] + bias[u * 4 + 0]);
                float fv = sigmoidf_(acc[u * 4 + 1] + bias[u * 4 + 1]);
                float gv = tanhf(acc[u * 4 + 2] + bias[u * 4 + 2]);
                float ov = sigmoidf_(acc[u * 4 + 3] + bias[u * 4 + 3]);
                int hu = hu0 + u;
                float* cp = cbuf + ((size_t)(l * HH + hu) << 6) + lane_b;
                float c = (t == 0) ? 0.0f : *cp;
                c = fv * c + iv * gv;
                *cp = c;
                float hval = ov * tanhf(c);
                if (l < 2) {
                    traj_out[((size_t)t * HH + hu) * BB + lane_b] = hval;
                } else {
                    h2pp[((size_t)(t & 1) * HH + hu) * BB + lane_b] = hval;
                }
            }
        }
        grid_barrier(bar, NBLK);
    }

    // ---- final FC on last hidden state of layer 2 ----
    if (blockIdx.x == 0 && threadIdx.x < BB) {
        int b = threadIdx.x;
        const float* h2 = h2pp + (size_t)((TT - 1) & 1) * HH * BB;
        float s = fcb[0];
        for (int k = 0; k < HH; ++k) {
            s = fmaf(h2[(k << 6) + b], fcw[k], s);
        }
        out[b] = s;
    }
}

extern "C" void kernel_launch(void* const* d_in, const int* in_sizes, int n_in,
                              void* d_out, int out_size, void* d_ws, size_t ws_size,
                              hipStream_t stream) {
    (void)in_sizes; (void)n_in; (void)out_size; (void)ws_size;

    const float* x    = (const float*)d_in[0];
    const float* Wih0 = (const float*)d_in[1];
    const float* Whh0 = (const float*)d_in[2];
    const float* bih0 = (const float*)d_in[3];
    const float* bhh0 = (const float*)d_in[4];
    const float* Wih1 = (const float*)d_in[5];
    const float* Whh1 = (const float*)d_in[6];
    const float* bih1 = (const float*)d_in[7];
    const float* bhh1 = (const float*)d_in[8];
    const float* Wih2 = (const float*)d_in[9];
    const float* Whh2 = (const float*)d_in[10];
    const float* bih2 = (const float*)d_in[11];
    const float* bhh2 = (const float*)d_in[12];
    const float* fcw  = (const float*)d_in[13];
    const float* fcb  = (const float*)d_in[14];

    float* ws = (float*)d_ws;
    // layout: [bar: 32 floats][cbuf: 3*H*B][h2pp: 2*H*B][xT: T*I*B][trajA: T*H*B][trajB: T*H*B]
    unsigned* bar = (unsigned*)d_ws;
    float* cbuf  = ws + 32;
    float* h2pp  = cbuf + 3 * HH * BB;
    float* xT    = h2pp + 2 * HH * BB;
    float* trajA = xT + (size_t)TT * II * BB;
    float* trajB = trajA + (size_t)TT * HH * BB;

    // zero barrier + cell state + h2 ping-pong (capture-safe)
    size_t zero_bytes = (32 + 3 * HH * BB + 2 * HH * BB) * sizeof(float);
    hipMemsetAsync(d_ws, 0, zero_bytes, stream);

    transpose_x_kernel<<<TT, 256, 0, stream>>>(x, xT);

    lstm_wavefront<<<NBLK, 256, 0, stream>>>(
        xT, trajA, trajB, cbuf, h2pp, bar,
        Wih0, Whh0, bih0, bhh0,
        Wih1, Whh1, bih1, bhh1,
        Wih2, Whh2, bih2, bhh2,
        fcw, fcb, (float*)d_out);
}

// Round 2
// 45046.799 us; speedup vs baseline: 1.9208x; 1.9208x over previous
//
#include <hip/hip_runtime.h>
#include <math.h>

#define BB 64      // batch
#define TT 512     // time steps
#define II 64      // input dim (layer 0)
#define HH 512     // hidden dim
#define NBLK 192   // 3 layers * 64 blocks
#define NWAVES (TT + 2)

__device__ __forceinline__ float sigmoidf_(float x) {
    return 1.0f / (1.0f + expf(-x));
}

// Sense-reversal grid barrier; cnt at bar[0], gen at bar[16].
__device__ __forceinline__ void grid_barrier(unsigned* bar) {
    __syncthreads();
    if (threadIdx.x == 0) {
        __threadfence();
        unsigned g = __hip_atomic_load(bar + 16, __ATOMIC_RELAXED, __HIP_MEMORY_SCOPE_AGENT);
        unsigned arrived = __hip_atomic_fetch_add(bar, 1u, __ATOMIC_ACQ_REL, __HIP_MEMORY_SCOPE_AGENT);
        if (arrived == NBLK - 1) {
            __hip_atomic_store(bar, 0u, __ATOMIC_RELAXED, __HIP_MEMORY_SCOPE_AGENT);
            __hip_atomic_fetch_add(bar + 16, 1u, __ATOMIC_RELEASE, __HIP_MEMORY_SCOPE_AGENT);
        } else {
            while (__hip_atomic_load(bar + 16, __ATOMIC_ACQUIRE, __HIP_MEMORY_SCOPE_AGENT) == g)
                __builtin_amdgcn_s_sleep(2);
        }
        __threadfence();
    }
    __syncthreads();
}

// x [B,T,I] -> xT [T][I][B]
__global__ __launch_bounds__(256) void transpose_x_kernel(
    const float* __restrict__ x, float* __restrict__ xT) {
    __shared__ float tile[64][65];
    int t = blockIdx.x;
    int a = threadIdx.x & 63;
    int q = threadIdx.x >> 6;
    #pragma unroll
    for (int r = 0; r < 16; ++r) {
        int bb = q * 16 + r;
        tile[a][bb] = x[((size_t)bb * TT + t) * II + a];
    }
    __syncthreads();
    #pragma unroll
    for (int r = 0; r < 16; ++r) {
        int ii = q * 16 + r;
        xT[((size_t)t * II + ii) * BB + a] = tile[ii][a];
    }
}

// Per-block: 8 h-units (32 gate rows) of one layer, weights resident in LDS
// (fence-immune). Each wave computes ALL 32 rows over a K/4 slice; partials
// reduced via LDS in two 16-row phases; cell update thread-local per (h,b).
template<int IN_DIM, int LAYER>
__device__ void lstm_core(int tile,
    const float* __restrict__ xin,   // [T][IN_DIM][B]
    float* __restrict__ hout,        // traj [T][H][B] (LAYER<2)
    float* __restrict__ h2pp,        // [2][H][B]      (LAYER==2)
    float* __restrict__ cbuf_l,      // [H][B] cell state for this layer
    const float* __restrict__ Wih, const float* __restrict__ Whh,
    const float* __restrict__ bih, const float* __restrict__ bhh,
    unsigned* __restrict__ bar,
    float* __restrict__ Wc, float* __restrict__ part, float* __restrict__ bias_lds)
{
    constexpr int KT = IN_DIM + HH;
    constexpr int K4 = KT / 4;
    const int tid = threadIdx.x;
    const int lane = tid & 63;   // batch
    const int hq = tid >> 6;     // wave id 0..3 (K-slice)
    const int hbase = tile * 8;

    // ---- stage weights into LDS once: row r = local_h*4 + gate ----
    for (int r = 0; r < 32; ++r) {
        const int lh = r >> 2, g = r & 3;
        const int grow = g * HH + hbase + lh;
        const float* wi = Wih + (size_t)grow * IN_DIM;
        const float* wh = Whh + (size_t)grow * HH;
        for (int e = tid; e < KT; e += 256)
            Wc[r * KT + e] = (e < IN_DIM) ? wi[e] : wh[e - IN_DIM];
    }
    if (tid < 32) {
        const int lh = tid >> 2, g = tid & 3;
        const int grow = g * HH + hbase + lh;
        bias_lds[tid] = bih[grow] + bhh[grow];
    }
    __syncthreads();

    // this wave's K-slice [lo,hi) split into x-part and h-part
    const int lo = hq * K4, hi = lo + K4;
    const int xa = (lo < IN_DIM) ? lo : IN_DIM;
    const int xb = (hi < IN_DIM) ? hi : IN_DIM;
    const int ha = ((lo > IN_DIM) ? lo : IN_DIM) - IN_DIM;
    const int hb = hi - IN_DIM;

    for (int w = 0; w < NWAVES; ++w) {
        const int t = w - LAYER;
        if (t >= 0 && t < TT) {
            float acc[32];
            #pragma unroll
            for (int r = 0; r < 32; ++r) acc[r] = 0.f;

            // x-part of the K slice
            {
                const float* p = xin + (size_t)t * IN_DIM * BB + lane;
                #pragma unroll 4
                for (int k = xa; k < xb; k += 4) {
                    const float f0 = p[(k + 0) * BB];
                    const float f1 = p[(k + 1) * BB];
                    const float f2 = p[(k + 2) * BB];
                    const float f3 = p[(k + 3) * BB];
                    #pragma unroll
                    for (int r = 0; r < 32; ++r) {
                        const float4 wv = *(const float4*)&Wc[r * KT + k];
                        acc[r] = fmaf(f3, wv.w, fmaf(f2, wv.z, fmaf(f1, wv.y, fmaf(f0, wv.x, acc[r]))));
                    }
                }
            }
            // h-part of the K slice (h_{t-1} = 0 at t==0)
            if (t > 0 && hb > ha) {
                const float* hp = (LAYER == 2) ? (h2pp + (size_t)((t - 1) & 1) * HH * BB)
                                               : (hout + (size_t)(t - 1) * HH * BB);
                const float* p = hp + lane;
                #pragma unroll 4
                for (int k = ha; k < hb; k += 4) {
                    const float f0 = p[(k + 0) * BB];
                    const float f1 = p[(k + 1) * BB];
                    const float f2 = p[(k + 2) * BB];
                    const float f3 = p[(k + 3) * BB];
                    #pragma unroll
                    for (int r = 0; r < 32; ++r) {
                        const float4 wv = *(const float4*)&Wc[r * KT + (k + IN_DIM)];
                        acc[r] = fmaf(f3, wv.w, fmaf(f2, wv.z, fmaf(f1, wv.y, fmaf(f0, wv.x, acc[r]))));
                    }
                }
            }

            // ---- 4-way cross-wave reduction + cell update, two 16-row phases ----
            #pragma unroll
            for (int ph = 0; ph < 2; ++ph) {
                #pragma unroll
                for (int r = 0; r < 16; ++r)
                    part[(hq * 16 + r) * BB + lane] = acc[ph * 16 + r];
                __syncthreads();
                float gs[4];
                #pragma unroll
                for (int g = 0; g < 4; ++g) {
                    const int rp = (hq * 4 + g) * BB + lane;
                    gs[g] = part[rp] + part[16 * BB + rp] + part[32 * BB + rp] + part[48 * BB + rp];
                }
                const int lh = ph * 4 + hq;
                const int r0 = lh * 4;
                const float iv = sigmoidf_(gs[0] + bias_lds[r0 + 0]);
                const float fv = sigmoidf_(gs[1] + bias_lds[r0 + 1]);
                const float gv = tanhf   (gs[2] + bias_lds[r0 + 2]);
                const float ov = sigmoidf_(gs[3] + bias_lds[r0 + 3]);
                const int hu = hbase + lh;
                float* cp = cbuf_l + (hu << 6) + lane;
                float c = (t == 0) ? 0.f : *cp;
                c = fv * c + iv * gv;
                *cp = c;
                const float hval = ov * tanhf(c);
                if (LAYER < 2) hout[((size_t)t * HH + hu) * BB + lane] = hval;
                else h2pp[((size_t)(t & 1) * HH + hu) * BB + lane] = hval;
                if (ph == 0) __syncthreads();  // part[] reads done before phase-B writes
            }
        }
        grid_barrier(bar);
    }
}

__global__ __launch_bounds__(256, 1) void lstm_wavefront(
    const float* __restrict__ xT,
    float* __restrict__ trajA, float* __restrict__ trajB,
    float* __restrict__ cbuf, float* __restrict__ h2pp, unsigned* __restrict__ bar,
    const float* __restrict__ Wih0, const float* __restrict__ Whh0,
    const float* __restrict__ bih0, const float* __restrict__ bhh0,
    const float* __restrict__ Wih1, const float* __restrict__ Whh1,
    const float* __restrict__ bih1, const float* __restrict__ bhh1,
    const float* __restrict__ Wih2, const float* __restrict__ Whh2,
    const float* __restrict__ bih2, const float* __restrict__ bhh2,
    const float* __restrict__ fcw, const float* __restrict__ fcb,
    float* __restrict__ out)
{
    __shared__ float Wc[32 * 1024];     // 128 KB (layer0 uses 32*576)
    __shared__ float part[64 * 64];     // 16 KB  [4 waves][16 rows][64 b]
    __shared__ float bias_lds[32];

    const int l = blockIdx.x >> 6;
    const int tile = blockIdx.x & 63;

    if (l == 0)
        lstm_core<II, 0>(tile, xT, trajA, h2pp, cbuf,
                         Wih0, Whh0, bih0, bhh0, bar, Wc, part, bias_lds);
    else if (l == 1)
        lstm_core<HH, 1>(tile, trajA, trajB, h2pp, cbuf + HH * BB,
                         Wih1, Whh1, bih1, bhh1, bar, Wc, part, bias_lds);
    else
        lstm_core<HH, 2>(tile, trajB, nullptr, h2pp, cbuf + 2 * HH * BB,
                         Wih2, Whh2, bih2, bhh2, bar, Wc, part, bias_lds);

    // final FC on last hidden state of layer 2
    if (blockIdx.x == 0 && threadIdx.x < BB) {
        const int b = threadIdx.x;
        const float* h2 = h2pp + (size_t)((TT - 1) & 1) * HH * BB;
        float s = fcb[0];
        for (int k = 0; k < HH; ++k)
            s = fmaf(h2[(k << 6) + b], fcw[k], s);
        out[b] = s;
    }
}

extern "C" void kernel_launch(void* const* d_in, const int* in_sizes, int n_in,
                              void* d_out, int out_size, void* d_ws, size_t ws_size,
                              hipStream_t stream) {
    (void)in_sizes; (void)n_in; (void)out_size; (void)ws_size;

    const float* x    = (const float*)d_in[0];
    const float* Wih0 = (const float*)d_in[1];
    const float* Whh0 = (const float*)d_in[2];
    const float* bih0 = (const float*)d_in[3];
    const float* bhh0 = (const float*)d_in[4];
    const float* Wih1 = (const float*)d_in[5];
    const float* Whh1 = (const float*)d_in[6];
    const float* bih1 = (const float*)d_in[7];
    const float* bhh1 = (const float*)d_in[8];
    const float* Wih2 = (const float*)d_in[9];
    const float* Whh2 = (const float*)d_in[10];
    const float* bih2 = (const float*)d_in[11];
    const float* bhh2 = (const float*)d_in[12];
    const float* fcw  = (const float*)d_in[13];
    const float* fcb  = (const float*)d_in[14];

    float* ws = (float*)d_ws;
    unsigned* bar = (unsigned*)d_ws;
    float* cbuf  = ws + 32;
    float* h2pp  = cbuf + 3 * HH * BB;
    float* xT    = h2pp + 2 * HH * BB;
    float* trajA = xT + (size_t)TT * II * BB;
    float* trajB = trajA + (size_t)TT * HH * BB;

    size_t zero_bytes = (32 + 3 * HH * BB + 2 * HH * BB) * sizeof(float);
    hipMemsetAsync(d_ws, 0, zero_bytes, stream);

    transpose_x_kernel<<<TT, 256, 0, stream>>>(x, xT);

    lstm_wavefront<<<NBLK, 256, 0, stream>>>(
        xT, trajA, trajB, cbuf, h2pp, bar,
        Wih0, Whh0, bih0, bhh0,
        Wih1, Whh1, bih1, bhh1,
        Wih2, Whh2, bih2, bhh2,
        fcw, fcb, (float*)d_out);
}

// Round 3
// 17419.331 us; speedup vs baseline: 4.9671x; 2.5860x over previous
//
#include <hip/hip_runtime.h>
#include <math.h>

#define BB 64
#define TT 512
#define II 64
#define HH 512
#define NBLK 192
#define NWAVES (TT + 2)

typedef __attribute__((ext_vector_type(8))) short bf16x8;
typedef __attribute__((ext_vector_type(16))) float f32x16;

__device__ __forceinline__ float sigmoidf_(float x) {
    return 1.0f / (1.0f + expf(-x));
}

__device__ __forceinline__ unsigned short f2bf(float f) {
    union { float f; unsigned u; } v; v.f = f;
    unsigned r = v.u + 0x7fffu + ((v.u >> 16) & 1u);   // RTNE (inputs never NaN/Inf)
    return (unsigned short)(r >> 16);
}
__device__ __forceinline__ float bf2f(unsigned short s) {
    union { unsigned u; float f; } v; v.u = ((unsigned)s) << 16;
    return v.f;
}

// Sense-reversal grid barrier. Per-thread store drain + block-master agent fences.
__device__ __forceinline__ void grid_barrier(unsigned* bar) {
    __builtin_amdgcn_s_waitcnt(0);       // drain this thread's stores
    __syncthreads();
    if (threadIdx.x == 0) {
        __threadfence();                 // release (wb L2)
        unsigned g = __hip_atomic_load(bar + 16, __ATOMIC_RELAXED, __HIP_MEMORY_SCOPE_AGENT);
        unsigned arrived = __hip_atomic_fetch_add(bar, 1u, __ATOMIC_ACQ_REL, __HIP_MEMORY_SCOPE_AGENT);
        if (arrived == NBLK - 1) {
            __hip_atomic_store(bar, 0u, __ATOMIC_RELAXED, __HIP_MEMORY_SCOPE_AGENT);
            __hip_atomic_fetch_add(bar + 16, 1u, __ATOMIC_RELEASE, __HIP_MEMORY_SCOPE_AGENT);
        } else {
            while (__hip_atomic_load(bar + 16, __ATOMIC_ACQUIRE, __HIP_MEMORY_SCOPE_AGENT) == g)
                __builtin_amdgcn_s_sleep(1);
        }
        __threadfence();                 // acquire (inv L1/L2)
    }
    __syncthreads();
}

// x [B,T,I] -> xTq [t][grp][b][hi 16B | lo 16B], grp = i>>3
__global__ __launch_bounds__(256) void pack_x(const float* __restrict__ x,
                                              char* __restrict__ xTq) {
    const int t = blockIdx.x;
    const int b = threadIdx.x & 63;
    const int gq = threadIdx.x >> 6;
    #pragma unroll
    for (int gi = 0; gi < 2; ++gi) {
        const int g2 = gq + gi * 4;
        const float* src = x + ((size_t)b * TT + t) * II + g2 * 8;
        float w[8];
        *(float4*)&w[0] = *(const float4*)src;
        *(float4*)&w[4] = *(const float4*)(src + 4);
        bf16x8 hv, lv;
        #pragma unroll
        for (int j = 0; j < 8; ++j) {
            unsigned short h = f2bf(w[j]);
            hv[j] = (short)h;
            lv[j] = (short)f2bf(w[j] - bf2f(h));
        }
        char* dst = xTq + (((size_t)t * 8 + g2) * 64 + b) * 32;
        *(bf16x8*)dst = hv;
        *(bf16x8*)(dst + 16) = lv;
    }
}

// MFMA over kstep range [S0,S1): A from LDS fragments, B from global (hi/lo 16B pairs).
// 3 independent accumulator chains (hi*hi, hi*lo, lo*hi).
template<int S0, int S1>
__device__ __forceinline__ void mfma_range(const char* __restrict__ bbase,
                                           const short* __restrict__ wa_lane,
                                           f32x16& c0, f32x16& c1, f32x16& c2) {
    #pragma unroll
    for (int s = S0; s < S1; ++s) {
        bf16x8 ahi = *(const bf16x8*)(wa_lane + (size_t)s * 1024);
        bf16x8 alo = *(const bf16x8*)(wa_lane + (size_t)s * 1024 + 8);
        bf16x8 bhi = *(const bf16x8*)(bbase + (size_t)s * 4096);
        bf16x8 blo = *(const bf16x8*)(bbase + (size_t)s * 4096 + 16);
        c0 = __builtin_amdgcn_mfma_f32_32x32x16_bf16(ahi, bhi, c0, 0, 0, 0);
        c1 = __builtin_amdgcn_mfma_f32_32x32x16_bf16(ahi, blo, c1, 0, 0, 0);
        c2 = __builtin_amdgcn_mfma_f32_32x32x16_bf16(alo, bhi, c2, 0, 0, 0);
    }
}

// Pack this block's 32 gate-rows (hi/lo bf16) into LDS in MFMA A-fragment order.
// row m = g*8+hl (lane&31), k = s*16 + (lane>>5)*8 + j  (same bijection as B).
template<int IN_DIM, int NKS>
__device__ void pack_weights(const float* __restrict__ Wih, const float* __restrict__ Whh,
                             int hbase, short* __restrict__ WA) {
    const int lane = threadIdx.x & 63;
    const int wq = threadIdx.x >> 6;
    const int m = lane & 31, lg = lane >> 5;
    const int grow = (m >> 3) * HH + hbase + (m & 7);
    const float* wi = Wih + (size_t)grow * IN_DIM;
    const float* wh = Whh + (size_t)grow * HH;
    for (int s = wq; s < NKS; s += 4) {
        const int k8 = s * 16 + lg * 8;
        const float* src = (k8 < IN_DIM) ? (wi + k8) : (wh + (k8 - IN_DIM));
        float w[8];
        *(float4*)&w[0] = *(const float4*)src;
        *(float4*)&w[4] = *(const float4*)(src + 4);
        bf16x8 hv, lv;
        #pragma unroll
        for (int j = 0; j < 8; ++j) {
            unsigned short h = f2bf(w[j]);
            hv[j] = (short)h;
            lv[j] = (short)f2bf(w[j] - bf2f(h));
        }
        short* dst = WA + ((size_t)s * 64 + lane) * 16;
        *(bf16x8*)dst = hv;
        *(bf16x8*)(dst + 8) = lv;
    }
}

// Ring layout per layer: [parity][grp][b][hi 16B | lo 16B]; grp = k>>3 over K = IN_DIM+HH.
// x-part grps [0, IN_DIM/8) written by upstream layer; h-part grps [XGRP, XGRP+64) own.
template<int LAYER, int IN_DIM, int NKS, int KH, int G, int XGRP>
__device__ void lstm_core(int tile,
                          const char* __restrict__ xTq,
                          char* __restrict__ ringL, char* __restrict__ ringN,
                          float* __restrict__ h2last, unsigned* __restrict__ bar,
                          const float* __restrict__ Wih, const float* __restrict__ Whh,
                          const float* __restrict__ bih, const float* __restrict__ bhh,
                          short* __restrict__ WA, float* __restrict__ redbuf) {
    const int tid = threadIdx.x;
    const int lane = tid & 63;
    const int wq = tid >> 6;
    const int ntile = wq & 1;
    const int khalf = wq >> 1;
    const int lg = lane >> 5;          // consumer: k-subgroup; updater: row-half
    const int b = ntile * 32 + (lane & 31);
    const int hbase = tile * 8;

    pack_weights<IN_DIM, NKS>(Wih, Whh, hbase, WA);

    float bias_v[16];
    float cst[4] = {0.f, 0.f, 0.f, 0.f};
    if (khalf == 0) {
        #pragma unroll
        for (int g = 0; g < 4; ++g)
            #pragma unroll
            for (int j = 0; j < 4; ++j) {
                const int grow = g * HH + hbase + j + 4 * lg;
                bias_v[g * 4 + j] = bih[grow] + bhh[grow];
            }
    }
    __syncthreads();   // WA ready

    const short* wa_lane = WA + lane * 16;

    for (int w = 0; w < NWAVES; ++w) {
        const int t = w - LAYER;
        if (t >= 0 && t < TT) {
            f32x16 c0 = {0,0,0,0,0,0,0,0,0,0,0,0,0,0,0,0};
            f32x16 c1 = c0, c2 = c0;
            const char* rb = ringL + (((size_t)(t & 1) * G) * 64 + b) * 32 + (size_t)lg * 2048;

            if (t == 0) {
                if (khalf == 0) {
                    if (LAYER == 0) {
                        const char* xq = xTq + ((size_t)t * 8 * 64 + b) * 32 + (size_t)lg * 2048;
                        mfma_range<0, 4>(xq, wa_lane, c0, c1, c2);
                    } else {
                        mfma_range<0, KH>(rb, wa_lane, c0, c1, c2);
                    }
                }
            } else {
                if (khalf == 0) {
                    if (LAYER == 0) {
                        const char* xq = xTq + ((size_t)t * 8 * 64 + b) * 32 + (size_t)lg * 2048;
                        mfma_range<0, 4>(xq, wa_lane, c0, c1, c2);
                        mfma_range<4, KH>(rb, wa_lane, c0, c1, c2);
                    } else {
                        mfma_range<0, KH>(rb, wa_lane, c0, c1, c2);
                    }
                } else {
                    mfma_range<KH, NKS>(rb, wa_lane, c0, c1, c2);
                }
            }

            f32x16 cs = c0 + c1 + c2;

            if (khalf == 1) {
                float* pw = &redbuf[((size_t)ntile * 64 + lane) * 20];
                #pragma unroll
                for (int q = 0; q < 4; ++q) {
                    float4 v; v.x = cs[q*4+0]; v.y = cs[q*4+1]; v.z = cs[q*4+2]; v.w = cs[q*4+3];
                    *(float4*)(pw + q * 4) = v;
                }
            }
            __syncthreads();
            if (khalf == 0) {
                const float* pr = &redbuf[((size_t)ntile * 64 + lane) * 20];
                float gate[16];
                #pragma unroll
                for (int r = 0; r < 16; ++r) gate[r] = cs[r] + pr[r] + bias_v[r];

                unsigned short his[4], los[4];
                #pragma unroll
                for (int j = 0; j < 4; ++j) {
                    const float iv = sigmoidf_(gate[0 + j]);
                    const float fv = sigmoidf_(gate[4 + j]);
                    const float gv = tanhf(gate[8 + j]);
                    const float ov = sigmoidf_(gate[12 + j]);
                    cst[j] = fv * cst[j] + iv * gv;
                    const float hv = ov * tanhf(cst[j]);
                    his[j] = f2bf(hv);
                    los[j] = f2bf(hv - bf2f(his[j]));
                    if (LAYER == 2 && t == TT - 1)
                        h2last[(size_t)(hbase + j + 4 * lg) * 64 + b] = hv;
                }
                uint2 hi2, lo2;
                hi2.x = (unsigned)his[0] | ((unsigned)his[1] << 16);
                hi2.y = (unsigned)his[2] | ((unsigned)his[3] << 16);
                lo2.x = (unsigned)los[0] | ((unsigned)los[1] << 16);
                lo2.y = (unsigned)los[2] | ((unsigned)los[3] << 16);

                // own ring h-part, parity (t+1)&1 (consumed at t+1)
                char* d2 = ringL + (((size_t)((t + 1) & 1) * G + XGRP + tile) * 64 + b) * 32 + lg * 8;
                *(uint2*)d2 = hi2;
                *(uint2*)(d2 + 16) = lo2;
                if (LAYER < 2) {
                    // next layer's x-part, parity t&1 (consumed by it at same t)
                    char* d1 = ringN + (((size_t)(t & 1) * 128 + tile) * 64 + b) * 32 + lg * 8;
                    *(uint2*)d1 = hi2;
                    *(uint2*)(d1 + 16) = lo2;
                }
            }
        }
        grid_barrier(bar);
    }
}

__global__ __launch_bounds__(256, 1) void lstm_wavefront(
    const char* __restrict__ xTq,
    char* __restrict__ ring0, char* __restrict__ ring1, char* __restrict__ ring2,
    float* __restrict__ h2last, unsigned* __restrict__ bar,
    const float* __restrict__ Wih0, const float* __restrict__ Whh0,
    const float* __restrict__ bih0, const float* __restrict__ bhh0,
    const float* __restrict__ Wih1, const float* __restrict__ Whh1,
    const float* __restrict__ bih1, const float* __restrict__ bhh1,
    const float* __restrict__ Wih2, const float* __restrict__ Whh2,
    const float* __restrict__ bih2, const float* __restrict__ bhh2,
    const float* __restrict__ fcw, const float* __restrict__ fcb,
    float* __restrict__ out) {

    __shared__ short WA[64 * 64 * 16];     // 128 KB max (layer0 uses 36/64)
    __shared__ float redbuf[2 * 64 * 20];  // 10 KB, padded stride vs bank conflicts
    __shared__ float fcred[256];

    const int l = blockIdx.x >> 6;
    const int tile = blockIdx.x & 63;

    if (l == 0)
        lstm_core<0, II, 36, 18, 72, 8>(tile, xTq, ring0, ring1, h2last, bar,
                                        Wih0, Whh0, bih0, bhh0, WA, redbuf);
    else if (l == 1)
        lstm_core<1, HH, 64, 32, 128, 64>(tile, xTq, ring1, ring2, h2last, bar,
                                          Wih1, Whh1, bih1, bhh1, WA, redbuf);
    else
        lstm_core<2, HH, 64, 32, 128, 64>(tile, xTq, ring2, ring2, h2last, bar,
                                          Wih2, Whh2, bih2, bhh2, WA, redbuf);

    // final FC on h2[T-1]
    if (blockIdx.x == 0) {
        const int tid = threadIdx.x;
        const int b = tid & 63, kq = tid >> 6;
        float s = 0.f;
        const float* hp = h2last + (size_t)kq * 128 * 64 + b;
        const float* wp = fcw + kq * 128;
        #pragma unroll 8
        for (int k = 0; k < 128; ++k)
            s = fmaf(hp[(size_t)k * 64], wp[k], s);
        fcred[tid] = s;
        __syncthreads();
        if (tid < 64)
            out[tid] = fcred[tid] + fcred[64 + tid] + fcred[128 + tid] + fcred[192 + tid] + fcb[0];
    }
}

extern "C" void kernel_launch(void* const* d_in, const int* in_sizes, int n_in,
                              void* d_out, int out_size, void* d_ws, size_t ws_size,
                              hipStream_t stream) {
    (void)in_sizes; (void)n_in; (void)out_size; (void)ws_size;

    const float* x    = (const float*)d_in[0];
    const float* Wih0 = (const float*)d_in[1];
    const float* Whh0 = (const float*)d_in[2];
    const float* bih0 = (const float*)d_in[3];
    const float* bhh0 = (const float*)d_in[4];
    const float* Wih1 = (const float*)d_in[5];
    const float* Whh1 = (const float*)d_in[6];
    const float* bih1 = (const float*)d_in[7];
    const float* bhh1 = (const float*)d_in[8];
    const float* Wih2 = (const float*)d_in[9];
    const float* Whh2 = (const float*)d_in[10];
    const float* bih2 = (const float*)d_in[11];
    const float* bhh2 = (const float*)d_in[12];
    const float* fcw  = (const float*)d_in[13];
    const float* fcb  = (const float*)d_in[14];

    char* ws = (char*)d_ws;
    unsigned* bar  = (unsigned*)ws;                        // 128 B
    char* ring0    = ws + 128;                             // 2*72*64*32  = 294912
    char* ring1    = ring0 + 2 * 72 * 64 * 32;             // 2*128*64*32 = 524288
    char* ring2    = ring1 + 2 * 128 * 64 * 32;
    float* h2last  = (float*)(ring2 + 2 * 128 * 64 * 32);  // 512*64*4
    char* xTq      = (char*)h2last + 512 * 64 * 4;         // 512*8*64*32 = 8 MB

    hipMemsetAsync(bar, 0, 128, stream);

    pack_x<<<TT, 256, 0, stream>>>(x, xTq);

    lstm_wavefront<<<NBLK, 256, 0, stream>>>(
        xTq, ring0, ring1, ring2, h2last, bar,
        Wih0, Whh0, bih0, bhh0,
        Wih1, Whh1, bih1, bhh1,
        Wih2, Whh2, bih2, bhh2,
        fcw, fcb, (float*)d_out);
}

// Round 4
// 7087.265 us; speedup vs baseline: 12.2084x; 2.4578x over previous
//
#include <hip/hip_runtime.h>
#include <math.h>

#define BB 64
#define TT 512
#define II 64
#define HH 512
#define NBLK 192
#define NWAVES (TT + 2)

typedef __attribute__((ext_vector_type(8))) short bf16x8;
typedef __attribute__((ext_vector_type(16))) float f32x16;

__device__ __forceinline__ float sigmoidf_(float x) {
    return 1.0f / (1.0f + expf(-x));
}

__device__ __forceinline__ unsigned short f2bf(float f) {
    union { float f; unsigned u; } v; v.f = f;
    unsigned r = v.u + 0x7fffu + ((v.u >> 16) & 1u);   // RTNE (inputs never NaN/Inf)
    return (unsigned short)(r >> 16);
}
__device__ __forceinline__ float bf2f(unsigned short s) {
    union { unsigned u; float f; } v; v.u = ((unsigned)s) << 16;
    return v.f;
}

// --- fence-free coherent primitives (agent scope -> sc0 sc1 bypass ops) ---
__device__ __forceinline__ void store8_thru(void* p, unsigned long long u) {
    __hip_atomic_store((unsigned long long*)p, u, __ATOMIC_RELAXED, __HIP_MEMORY_SCOPE_AGENT);
}
__device__ __forceinline__ bf16x8 load16_byp(const void* p) {
    union { unsigned long long u[2]; bf16x8 v; } r;
    r.u[0] = __hip_atomic_load((const unsigned long long*)p, __ATOMIC_RELAXED, __HIP_MEMORY_SCOPE_AGENT);
    r.u[1] = __hip_atomic_load((const unsigned long long*)((const char*)p + 8), __ATOMIC_RELAXED, __HIP_MEMORY_SCOPE_AGENT);
    return r.v;
}
__device__ __forceinline__ void storef_thru(float* p, float v) {
    __hip_atomic_store(p, v, __ATOMIC_RELAXED, __HIP_MEMORY_SCOPE_AGENT);
}
__device__ __forceinline__ float loadf_byp(const float* p) {
    return __hip_atomic_load(p, __ATOMIC_RELAXED, __HIP_MEMORY_SCOPE_AGENT);
}

// Tree grid barrier, all-relaxed atomics, NO cache-maintenance fences.
// bar[32*k] k=0..7 sub-counters (24 blocks each); bar[256] root; bar[288] gen.
__device__ __forceinline__ void grid_barrier(unsigned* bar, int sub) {
    __builtin_amdgcn_s_waitcnt(0);   // each wave drains its own (write-through) stores
    __syncthreads();
    if (threadIdx.x == 0) {
        unsigned* gen = bar + 288;
        const unsigned g = __hip_atomic_load(gen, __ATOMIC_RELAXED, __HIP_MEMORY_SCOPE_AGENT);
        const unsigned a = __hip_atomic_fetch_add(bar + 32 * sub, 1u, __ATOMIC_RELAXED, __HIP_MEMORY_SCOPE_AGENT);
        if (a == 23) {
            __hip_atomic_store(bar + 32 * sub, 0u, __ATOMIC_RELAXED, __HIP_MEMORY_SCOPE_AGENT);
            const unsigned r = __hip_atomic_fetch_add(bar + 256, 1u, __ATOMIC_RELAXED, __HIP_MEMORY_SCOPE_AGENT);
            if (r == 7) {
                __hip_atomic_store(bar + 256, 0u, __ATOMIC_RELAXED, __HIP_MEMORY_SCOPE_AGENT);
                __hip_atomic_store(gen, g + 1u, __ATOMIC_RELAXED, __HIP_MEMORY_SCOPE_AGENT);
            }
        }
        while (__hip_atomic_load(gen, __ATOMIC_RELAXED, __HIP_MEMORY_SCOPE_AGENT) == g)
            __builtin_amdgcn_s_sleep(2);
    }
    __syncthreads();
}

// x [B,T,I] -> xTq [t][grp][b][hi 16B | lo 16B], grp = i>>3
__global__ __launch_bounds__(256) void pack_x(const float* __restrict__ x,
                                              char* __restrict__ xTq) {
    const int t = blockIdx.x;
    const int b = threadIdx.x & 63;
    const int gq = threadIdx.x >> 6;
    #pragma unroll
    for (int gi = 0; gi < 2; ++gi) {
        const int g2 = gq + gi * 4;
        const float* src = x + ((size_t)b * TT + t) * II + g2 * 8;
        float w[8];
        *(float4*)&w[0] = *(const float4*)src;
        *(float4*)&w[4] = *(const float4*)(src + 4);
        bf16x8 hv, lv;
        #pragma unroll
        for (int j = 0; j < 8; ++j) {
            unsigned short h = f2bf(w[j]);
            hv[j] = (short)h;
            lv[j] = (short)f2bf(w[j] - bf2f(h));
        }
        char* dst = xTq + (((size_t)t * 8 + g2) * 64 + b) * 32;
        *(bf16x8*)dst = hv;
        *(bf16x8*)(dst + 16) = lv;
    }
}

// MFMA over kstep range [S0,S1), B from ring via L1/L2-bypass loads.
template<int S0, int S1>
__device__ __forceinline__ void mfma_ring(const char* __restrict__ bbase,
                                          const short* __restrict__ wa_lane,
                                          f32x16& c0, f32x16& c1, f32x16& c2) {
    #pragma unroll
    for (int s = S0; s < S1; ++s) {
        bf16x8 ahi = *(const bf16x8*)(wa_lane + (size_t)s * 1024);
        bf16x8 alo = *(const bf16x8*)(wa_lane + (size_t)s * 1024 + 8);
        bf16x8 bhi = load16_byp(bbase + (size_t)s * 4096);
        bf16x8 blo = load16_byp(bbase + (size_t)s * 4096 + 16);
        c0 = __builtin_amdgcn_mfma_f32_32x32x16_bf16(ahi, bhi, c0, 0, 0, 0);
        c1 = __builtin_amdgcn_mfma_f32_32x32x16_bf16(ahi, blo, c1, 0, 0, 0);
        c2 = __builtin_amdgcn_mfma_f32_32x32x16_bf16(alo, bhi, c2, 0, 0, 0);
    }
}

// Same but B from read-only xTq (plain cached loads).
template<int S0, int S1>
__device__ __forceinline__ void mfma_x(const char* __restrict__ bbase,
                                       const short* __restrict__ wa_lane,
                                       f32x16& c0, f32x16& c1, f32x16& c2) {
    #pragma unroll
    for (int s = S0; s < S1; ++s) {
        bf16x8 ahi = *(const bf16x8*)(wa_lane + (size_t)s * 1024);
        bf16x8 alo = *(const bf16x8*)(wa_lane + (size_t)s * 1024 + 8);
        bf16x8 bhi = *(const bf16x8*)(bbase + (size_t)s * 4096);
        bf16x8 blo = *(const bf16x8*)(bbase + (size_t)s * 4096 + 16);
        c0 = __builtin_amdgcn_mfma_f32_32x32x16_bf16(ahi, bhi, c0, 0, 0, 0);
        c1 = __builtin_amdgcn_mfma_f32_32x32x16_bf16(ahi, blo, c1, 0, 0, 0);
        c2 = __builtin_amdgcn_mfma_f32_32x32x16_bf16(alo, bhi, c2, 0, 0, 0);
    }
}

// Pack this block's 32 gate-rows (hi/lo bf16) into LDS in MFMA A-fragment order.
template<int IN_DIM, int NKS>
__device__ void pack_weights(const float* __restrict__ Wih, const float* __restrict__ Whh,
                             int hbase, short* __restrict__ WA) {
    const int lane = threadIdx.x & 63;
    const int wq = threadIdx.x >> 6;
    const int m = lane & 31, lg = lane >> 5;
    const int grow = (m >> 3) * HH + hbase + (m & 7);
    const float* wi = Wih + (size_t)grow * IN_DIM;
    const float* wh = Whh + (size_t)grow * HH;
    for (int s = wq; s < NKS; s += 4) {
        const int k8 = s * 16 + lg * 8;
        const float* src = (k8 < IN_DIM) ? (wi + k8) : (wh + (k8 - IN_DIM));
        float w[8];
        *(float4*)&w[0] = *(const float4*)src;
        *(float4*)&w[4] = *(const float4*)(src + 4);
        bf16x8 hv, lv;
        #pragma unroll
        for (int j = 0; j < 8; ++j) {
            unsigned short h = f2bf(w[j]);
            hv[j] = (short)h;
            lv[j] = (short)f2bf(w[j] - bf2f(h));
        }
        short* dst = WA + ((size_t)s * 64 + lane) * 16;
        *(bf16x8*)dst = hv;
        *(bf16x8*)(dst + 8) = lv;
    }
}

// Ring layout per layer: [parity][grp][b][hi 16B | lo 16B]; grp = k>>3.
template<int LAYER, int IN_DIM, int NKS, int KH, int G, int XGRP>
__device__ void lstm_core(int tile, int sub,
                          const char* __restrict__ xTq,
                          char* __restrict__ ringL, char* __restrict__ ringN,
                          float* __restrict__ h2last, unsigned* __restrict__ bar,
                          const float* __restrict__ Wih, const float* __restrict__ Whh,
                          const float* __restrict__ bih, const float* __restrict__ bhh,
                          short* __restrict__ WA, float* __restrict__ redbuf) {
    const int tid = threadIdx.x;
    const int lane = tid & 63;
    const int wq = tid >> 6;
    const int ntile = wq & 1;
    const int khalf = wq >> 1;
    const int lg = lane >> 5;
    const int b = ntile * 32 + (lane & 31);
    const int hbase = tile * 8;

    pack_weights<IN_DIM, NKS>(Wih, Whh, hbase, WA);

    float bias_v[16];
    float cst[4] = {0.f, 0.f, 0.f, 0.f};
    if (khalf == 0) {
        #pragma unroll
        for (int g = 0; g < 4; ++g)
            #pragma unroll
            for (int j = 0; j < 4; ++j) {
                const int grow = g * HH + hbase + j + 4 * lg;
                bias_v[g * 4 + j] = bih[grow] + bhh[grow];
            }
    }
    __syncthreads();   // WA ready

    const short* wa_lane = WA + lane * 16;

    for (int w = 0; w < NWAVES; ++w) {
        const int t = w - LAYER;
        if (t >= 0 && t < TT) {
            f32x16 c0 = {0,0,0,0,0,0,0,0,0,0,0,0,0,0,0,0};
            f32x16 c1 = c0, c2 = c0;
            const char* rb = ringL + (((size_t)(t & 1) * G) * 64 + b) * 32 + (size_t)lg * 2048;

            if (t == 0) {
                if (khalf == 0) {
                    if (LAYER == 0) {
                        const char* xq = xTq + ((size_t)t * 8 * 64 + b) * 32 + (size_t)lg * 2048;
                        mfma_x<0, 4>(xq, wa_lane, c0, c1, c2);
                    } else {
                        mfma_ring<0, KH>(rb, wa_lane, c0, c1, c2);
                    }
                }
            } else {
                if (khalf == 0) {
                    if (LAYER == 0) {
                        const char* xq = xTq + ((size_t)t * 8 * 64 + b) * 32 + (size_t)lg * 2048;
                        mfma_x<0, 4>(xq, wa_lane, c0, c1, c2);
                        mfma_ring<4, KH>(rb, wa_lane, c0, c1, c2);
                    } else {
                        mfma_ring<0, KH>(rb, wa_lane, c0, c1, c2);
                    }
                } else {
                    mfma_ring<KH, NKS>(rb, wa_lane, c0, c1, c2);
                }
            }

            f32x16 cs = c0 + c1 + c2;

            if (khalf == 1) {
                float* pw = &redbuf[((size_t)ntile * 64 + lane) * 20];
                #pragma unroll
                for (int q = 0; q < 4; ++q) {
                    float4 v; v.x = cs[q*4+0]; v.y = cs[q*4+1]; v.z = cs[q*4+2]; v.w = cs[q*4+3];
                    *(float4*)(pw + q * 4) = v;
                }
            }
            __syncthreads();
            if (khalf == 0) {
                const float* pr = &redbuf[((size_t)ntile * 64 + lane) * 20];
                float gate[16];
                #pragma unroll
                for (int r = 0; r < 16; ++r) gate[r] = cs[r] + pr[r] + bias_v[r];

                unsigned short his[4], los[4];
                #pragma unroll
                for (int j = 0; j < 4; ++j) {
                    const float iv = sigmoidf_(gate[0 + j]);
                    const float fv = sigmoidf_(gate[4 + j]);
                    const float gv = tanhf(gate[8 + j]);
                    const float ov = sigmoidf_(gate[12 + j]);
                    cst[j] = fv * cst[j] + iv * gv;
                    const float hv = ov * tanhf(cst[j]);
                    his[j] = f2bf(hv);
                    los[j] = f2bf(hv - bf2f(his[j]));
                    if (LAYER == 2 && t == TT - 1)
                        storef_thru(h2last + (size_t)(hbase + j + 4 * lg) * 64 + b, hv);
                }
                unsigned long long hi2 = (unsigned long long)((unsigned)his[0] | ((unsigned)his[1] << 16))
                                       | ((unsigned long long)((unsigned)his[2] | ((unsigned)his[3] << 16)) << 32);
                unsigned long long lo2 = (unsigned long long)((unsigned)los[0] | ((unsigned)los[1] << 16))
                                       | ((unsigned long long)((unsigned)los[2] | ((unsigned)los[3] << 16)) << 32);

                // own ring h-part, parity (t+1)&1 (consumed at t+1)
                char* d2 = ringL + (((size_t)((t + 1) & 1) * G + XGRP + tile) * 64 + b) * 32 + lg * 8;
                store8_thru(d2, hi2);
                store8_thru(d2 + 16, lo2);
                if (LAYER < 2) {
                    // next layer's x-part, parity t&1 (consumed by it at same t)
                    char* d1 = ringN + (((size_t)(t & 1) * 128 + tile) * 64 + b) * 32 + lg * 8;
                    store8_thru(d1, hi2);
                    store8_thru(d1 + 16, lo2);
                }
            }
        }
        grid_barrier(bar, sub);
    }
}

__global__ __launch_bounds__(256, 1) void lstm_wavefront(
    const char* __restrict__ xTq,
    char* __restrict__ ring0, char* __restrict__ ring1, char* __restrict__ ring2,
    float* __restrict__ h2last, unsigned* __restrict__ bar,
    const float* __restrict__ Wih0, const float* __restrict__ Whh0,
    const float* __restrict__ bih0, const float* __restrict__ bhh0,
    const float* __restrict__ Wih1, const float* __restrict__ Whh1,
    const float* __restrict__ bih1, const float* __restrict__ bhh1,
    const float* __restrict__ Wih2, const float* __restrict__ Whh2,
    const float* __restrict__ bih2, const float* __restrict__ bhh2,
    const float* __restrict__ fcw, const float* __restrict__ fcb,
    float* __restrict__ out) {

    __shared__ short WA[64 * 64 * 16];     // 128 KB max (layer0 uses 36/64)
    __shared__ float redbuf[2 * 64 * 20];  // 10 KB
    __shared__ float fcred[256];

    const int l = blockIdx.x >> 6;
    const int tile = blockIdx.x & 63;
    const int sub = blockIdx.x & 7;

    if (l == 0)
        lstm_core<0, II, 36, 18, 72, 8>(tile, sub, xTq, ring0, ring1, h2last, bar,
                                        Wih0, Whh0, bih0, bhh0, WA, redbuf);
    else if (l == 1)
        lstm_core<1, HH, 64, 32, 128, 64>(tile, sub, xTq, ring1, ring2, h2last, bar,
                                          Wih1, Whh1, bih1, bhh1, WA, redbuf);
    else
        lstm_core<2, HH, 64, 32, 128, 64>(tile, sub, xTq, ring2, ring2, h2last, bar,
                                          Wih2, Whh2, bih2, bhh2, WA, redbuf);

    // final FC on h2[T-1] (h2last written via write-through; read via bypass)
    if (blockIdx.x == 0) {
        const int tid = threadIdx.x;
        const int b = tid & 63, kq = tid >> 6;
        float s = 0.f;
        const float* hp = h2last + (size_t)kq * 128 * 64 + b;
        const float* wp = fcw + kq * 128;
        #pragma unroll 8
        for (int k = 0; k < 128; ++k)
            s = fmaf(loadf_byp(hp + (size_t)k * 64), wp[k], s);
        fcred[tid] = s;
        __syncthreads();
        if (tid < 64)
            out[tid] = fcred[tid] + fcred[64 + tid] + fcred[128 + tid] + fcred[192 + tid] + fcb[0];
    }
}

extern "C" void kernel_launch(void* const* d_in, const int* in_sizes, int n_in,
                              void* d_out, int out_size, void* d_ws, size_t ws_size,
                              hipStream_t stream) {
    (void)in_sizes; (void)n_in; (void)out_size; (void)ws_size;

    const float* x    = (const float*)d_in[0];
    const float* Wih0 = (const float*)d_in[1];
    const float* Whh0 = (const float*)d_in[2];
    const float* bih0 = (const float*)d_in[3];
    const float* bhh0 = (const float*)d_in[4];
    const float* Wih1 = (const float*)d_in[5];
    const float* Whh1 = (const float*)d_in[6];
    const float* bih1 = (const float*)d_in[7];
    const float* bhh1 = (const float*)d_in[8];
    const float* Wih2 = (const float*)d_in[9];
    const float* Whh2 = (const float*)d_in[10];
    const float* bih2 = (const float*)d_in[11];
    const float* bhh2 = (const float*)d_in[12];
    const float* fcw  = (const float*)d_in[13];
    const float* fcb  = (const float*)d_in[14];

    char* ws = (char*)d_ws;
    unsigned* bar  = (unsigned*)ws;                        // 4 KB (tree barrier)
    char* ring0    = ws + 4096;
    char* ring1    = ring0 + 2 * 72 * 64 * 32;
    char* ring2    = ring1 + 2 * 128 * 64 * 32;
    float* h2last  = (float*)(ring2 + 2 * 128 * 64 * 32);
    char* xTq      = (char*)h2last + 512 * 64 * 4;

    hipMemsetAsync(bar, 0, 4096, stream);

    pack_x<<<TT, 256, 0, stream>>>(x, xTq);

    lstm_wavefront<<<NBLK, 256, 0, stream>>>(
        xTq, ring0, ring1, ring2, h2last, bar,
        Wih0, Whh0, bih0, bhh0,
        Wih1, Whh1, bih1, bhh1,
        Wih2, Whh2, bih2, bhh2,
        fcw, fcb, (float*)d_out);
}

// Round 6
// 6162.220 us; speedup vs baseline: 14.0411x; 1.1501x over previous
//
#include <hip/hip_runtime.h>
#include <math.h>

#define BB 64
#define TT 512
#define II 64
#define HH 512
#define NBLK 192
#define NWAVES (TT + 2)

typedef __attribute__((ext_vector_type(8))) short bf16x8;
typedef __attribute__((ext_vector_type(16))) float f32x16;

__device__ __forceinline__ float sigmoidf_(float x) {
    return 1.0f / (1.0f + expf(-x));
}

__device__ __forceinline__ unsigned short f2bf(float f) {
    union { float f; unsigned u; } v; v.f = f;
    unsigned r = v.u + 0x7fffu + ((v.u >> 16) & 1u);   // RTNE (inputs never NaN/Inf)
    return (unsigned short)(r >> 16);
}
__device__ __forceinline__ float bf2f(unsigned short s) {
    union { unsigned u; float f; } v; v.u = ((unsigned)s) << 16;
    return v.f;
}

// --- fence-free coherent primitives (agent scope -> L1/L2-bypass ops the
// compiler's waitcnt pass tracks correctly, unlike inline-asm loads) ---
__device__ __forceinline__ bf16x8 load16_byp(const void* p) {
    union { unsigned long long u[2]; bf16x8 v; } r;
    r.u[0] = __hip_atomic_load((const unsigned long long*)p, __ATOMIC_RELAXED, __HIP_MEMORY_SCOPE_AGENT);
    r.u[1] = __hip_atomic_load((const unsigned long long*)((const char*)p + 8), __ATOMIC_RELAXED, __HIP_MEMORY_SCOPE_AGENT);
    return r.v;
}
__device__ __forceinline__ void store8_thru(void* p, unsigned long long u) {
    __hip_atomic_store((unsigned long long*)p, u, __ATOMIC_RELAXED, __HIP_MEMORY_SCOPE_AGENT);
}
__device__ __forceinline__ void storef_thru(float* p, float v) {
    __hip_atomic_store(p, v, __ATOMIC_RELAXED, __HIP_MEMORY_SCOPE_AGENT);
}
__device__ __forceinline__ float loadf_byp(const float* p) {
    return __hip_atomic_load(p, __ATOMIC_RELAXED, __HIP_MEMORY_SCOPE_AGENT);
}

// Tree grid barrier, all-relaxed atomics, no cache-maintenance fences.
__device__ __forceinline__ void grid_barrier(unsigned* bar, int sub) {
    __builtin_amdgcn_s_waitcnt(0);   // drain this wave's write-through stores
    __syncthreads();
    if (threadIdx.x == 0) {
        unsigned* gen = bar + 288;
        const unsigned g = __hip_atomic_load(gen, __ATOMIC_RELAXED, __HIP_MEMORY_SCOPE_AGENT);
        const unsigned a = __hip_atomic_fetch_add(bar + 32 * sub, 1u, __ATOMIC_RELAXED, __HIP_MEMORY_SCOPE_AGENT);
        if (a == 23) {
            __hip_atomic_store(bar + 32 * sub, 0u, __ATOMIC_RELAXED, __HIP_MEMORY_SCOPE_AGENT);
            const unsigned r = __hip_atomic_fetch_add(bar + 256, 1u, __ATOMIC_RELAXED, __HIP_MEMORY_SCOPE_AGENT);
            if (r == 7) {
                __hip_atomic_store(bar + 256, 0u, __ATOMIC_RELAXED, __HIP_MEMORY_SCOPE_AGENT);
                __hip_atomic_store(gen, g + 1u, __ATOMIC_RELAXED, __HIP_MEMORY_SCOPE_AGENT);
            }
        }
        while (__hip_atomic_load(gen, __ATOMIC_RELAXED, __HIP_MEMORY_SCOPE_AGENT) == g)
            __builtin_amdgcn_s_sleep(1);
    }
    __syncthreads();
}

// x [B,T,I] -> xTq [t][grp][b][hi 16B | lo 16B], grp = i>>3
__global__ __launch_bounds__(256) void pack_x(const float* __restrict__ x,
                                              char* __restrict__ xTq) {
    const int t = blockIdx.x;
    const int b = threadIdx.x & 63;
    const int gq = threadIdx.x >> 6;
    #pragma unroll
    for (int gi = 0; gi < 2; ++gi) {
        const int g2 = gq + gi * 4;
        const float* src = x + ((size_t)b * TT + t) * II + g2 * 8;
        float w[8];
        *(float4*)&w[0] = *(const float4*)src;
        *(float4*)&w[4] = *(const float4*)(src + 4);
        bf16x8 hv, lv;
        #pragma unroll
        for (int j = 0; j < 8; ++j) {
            unsigned short h = f2bf(w[j]);
            hv[j] = (short)h;
            lv[j] = (short)f2bf(w[j] - bf2f(h));
        }
        char* dst = xTq + (((size_t)t * 8 + g2) * 64 + b) * 32;
        *(bf16x8*)dst = hv;
        *(bf16x8*)(dst + 16) = lv;
    }
}

// One stage+consume phase over ksteps [S0,S1). ksteps < XEND read from xq
// (read-only, plain cached loads); the rest from the ring (bypass loads).
// All loads issued back-to-back into a register array, sched_barrier pins
// them above the MFMAs, compiler inserts ONE batched vmcnt wait at first use.
template<int S0, int S1, int XEND>
__device__ __forceinline__ void phase(const char* __restrict__ xq,
                                      const char* __restrict__ rb,
                                      const short* __restrict__ wa_lane,
                                      f32x16& c0, f32x16& c1, f32x16& c2) {
    constexpr int N = S1 - S0;
    bf16x8 bh[N], bl[N];
    #pragma unroll
    for (int s = S0; s < S1; ++s) {
        if (s < XEND) {
            bh[s - S0] = *(const bf16x8*)(xq + (size_t)s * 4096);
            bl[s - S0] = *(const bf16x8*)(xq + (size_t)s * 4096 + 16);
        } else {
            bh[s - S0] = load16_byp(rb + (size_t)s * 4096);
            bl[s - S0] = load16_byp(rb + (size_t)s * 4096 + 16);
        }
    }
    __builtin_amdgcn_sched_barrier(0);   // keep all loads above the MFMA block
    #pragma unroll
    for (int s = S0; s < S1; ++s) {
        bf16x8 ahi = *(const bf16x8*)(wa_lane + (size_t)s * 1024);
        bf16x8 alo = *(const bf16x8*)(wa_lane + (size_t)s * 1024 + 8);
        c0 = __builtin_amdgcn_mfma_f32_32x32x16_bf16(ahi, bh[s - S0], c0, 0, 0, 0);
        c1 = __builtin_amdgcn_mfma_f32_32x32x16_bf16(ahi, bl[s - S0], c1, 0, 0, 0);
        c2 = __builtin_amdgcn_mfma_f32_32x32x16_bf16(alo, bh[s - S0], c2, 0, 0, 0);
    }
}

// Pack this block's 32 gate-rows (hi/lo bf16) into LDS in MFMA A-fragment order.
template<int IN_DIM, int NKS>
__device__ void pack_weights(const float* __restrict__ Wih, const float* __restrict__ Whh,
                             int hbase, short* __restrict__ WA) {
    const int lane = threadIdx.x & 63;
    const int wq = threadIdx.x >> 6;
    const int m = lane & 31, lg = lane >> 5;
    const int grow = (m >> 3) * HH + hbase + (m & 7);
    const float* wi = Wih + (size_t)grow * IN_DIM;
    const float* wh = Whh + (size_t)grow * HH;
    for (int s = wq; s < NKS; s += 4) {
        const int k8 = s * 16 + lg * 8;
        const float* src = (k8 < IN_DIM) ? (wi + k8) : (wh + (k8 - IN_DIM));
        float w[8];
        *(float4*)&w[0] = *(const float4*)src;
        *(float4*)&w[4] = *(const float4*)(src + 4);
        bf16x8 hv, lv;
        #pragma unroll
        for (int j = 0; j < 8; ++j) {
            unsigned short h = f2bf(w[j]);
            hv[j] = (short)h;
            lv[j] = (short)f2bf(w[j] - bf2f(h));
        }
        short* dst = WA + ((size_t)s * 64 + lane) * 16;
        *(bf16x8*)dst = hv;
        *(bf16x8*)(dst + 8) = lv;
    }
}

// Ring layout per layer: [parity][grp][b][hi 16B | lo 16B]; grp = k>>3.
template<int LAYER, int IN_DIM, int NKS, int KH, int G, int XGRP>
__device__ void lstm_core(int tile, int sub,
                          const char* __restrict__ xTq,
                          char* __restrict__ ringL, char* __restrict__ ringN,
                          float* __restrict__ h2last, unsigned* __restrict__ bar,
                          const float* __restrict__ Wih, const float* __restrict__ Whh,
                          const float* __restrict__ bih, const float* __restrict__ bhh,
                          short* __restrict__ WA, float* __restrict__ redbuf) {
    const int tid = threadIdx.x;
    const int lane = tid & 63;
    const int wq = tid >> 6;
    const int ntile = wq & 1;
    const int khalf = wq >> 1;
    const int lg = lane >> 5;
    const int b = ntile * 32 + (lane & 31);
    const int hbase = tile * 8;

    pack_weights<IN_DIM, NKS>(Wih, Whh, hbase, WA);

    float bias_v[16];
    float cst[4] = {0.f, 0.f, 0.f, 0.f};
    if (khalf == 0) {
        #pragma unroll
        for (int g = 0; g < 4; ++g)
            #pragma unroll
            for (int j = 0; j < 4; ++j) {
                const int grow = g * HH + hbase + j + 4 * lg;
                bias_v[g * 4 + j] = bih[grow] + bhh[grow];
            }
    }
    __syncthreads();   // WA ready

    const short* wa_lane = WA + lane * 16;
    constexpr int KM = KH / 2;                 // mid of khalf-0 range
    constexpr int K3 = KH + (NKS - KH) / 2;    // mid of khalf-1 range

    for (int w = 0; w < NWAVES; ++w) {
        const int t = w - LAYER;
        if (t >= 0 && t < TT) {
            f32x16 c0 = {0,0,0,0,0,0,0,0,0,0,0,0,0,0,0,0};
            f32x16 c1 = c0, c2 = c0;
            const char* rb = ringL + (((size_t)(t & 1) * G) * 64 + b) * 32 + (size_t)lg * 2048;

            if (khalf == 0) {
                if (LAYER == 0) {
                    const char* xq = xTq + ((size_t)t * 8 * 64 + b) * 32 + (size_t)lg * 2048;
                    if (t > 0) {
                        phase<0, KM, 4>(xq, rb, wa_lane, c0, c1, c2);
                        phase<KM, KH, 4>(xq, rb, wa_lane, c0, c1, c2);
                    } else {
                        phase<0, 4, 4>(xq, rb, wa_lane, c0, c1, c2);
                    }
                } else {
                    // ksteps [0,KH) are the x-part (written by upstream) — valid at t==0 too
                    phase<0, KM, 0>(nullptr, rb, wa_lane, c0, c1, c2);
                    phase<KM, KH, 0>(nullptr, rb, wa_lane, c0, c1, c2);
                }
            } else {
                if (t > 0) {
                    phase<KH, K3, 0>(nullptr, rb, wa_lane, c0, c1, c2);
                    phase<K3, NKS, 0>(nullptr, rb, wa_lane, c0, c1, c2);
                }
            }

            f32x16 cs = c0 + c1 + c2;

            if (khalf == 1) {
                float* pw = &redbuf[((size_t)ntile * 64 + lane) * 20];
                #pragma unroll
                for (int q = 0; q < 4; ++q) {
                    float4 v; v.x = cs[q*4+0]; v.y = cs[q*4+1]; v.z = cs[q*4+2]; v.w = cs[q*4+3];
                    *(float4*)(pw + q * 4) = v;
                }
            }
            __syncthreads();
            if (khalf == 0) {
                const float* pr = &redbuf[((size_t)ntile * 64 + lane) * 20];
                float gate[16];
                #pragma unroll
                for (int r = 0; r < 16; ++r) gate[r] = cs[r] + pr[r] + bias_v[r];

                unsigned short his[4], los[4];
                #pragma unroll
                for (int j = 0; j < 4; ++j) {
                    const float iv = sigmoidf_(gate[0 + j]);
                    const float fv = sigmoidf_(gate[4 + j]);
                    const float gv = tanhf(gate[8 + j]);
                    const float ov = sigmoidf_(gate[12 + j]);
                    cst[j] = fv * cst[j] + iv * gv;
                    const float hv = ov * tanhf(cst[j]);
                    his[j] = f2bf(hv);
                    los[j] = f2bf(hv - bf2f(his[j]));
                    if (LAYER == 2 && t == TT - 1)
                        storef_thru(h2last + (size_t)(hbase + j + 4 * lg) * 64 + b, hv);
                }
                unsigned long long hi2 = (unsigned long long)((unsigned)his[0] | ((unsigned)his[1] << 16))
                                       | ((unsigned long long)((unsigned)his[2] | ((unsigned)his[3] << 16)) << 32);
                unsigned long long lo2 = (unsigned long long)((unsigned)los[0] | ((unsigned)los[1] << 16))
                                       | ((unsigned long long)((unsigned)los[2] | ((unsigned)los[3] << 16)) << 32);

                // own ring h-part, parity (t+1)&1 (consumed at t+1)
                char* d2 = ringL + (((size_t)((t + 1) & 1) * G + XGRP + tile) * 64 + b) * 32 + lg * 8;
                store8_thru(d2, hi2);
                store8_thru(d2 + 16, lo2);
                if (LAYER < 2) {
                    // next layer's x-part, parity t&1 (consumed by it at same t)
                    char* d1 = ringN + (((size_t)(t & 1) * 128 + tile) * 64 + b) * 32 + lg * 8;
                    store8_thru(d1, hi2);
                    store8_thru(d1 + 16, lo2);
                }
            }
        }
        grid_barrier(bar, sub);
    }
}

__global__ __launch_bounds__(256, 1) void lstm_wavefront(
    const char* __restrict__ xTq,
    char* __restrict__ ring0, char* __restrict__ ring1, char* __restrict__ ring2,
    float* __restrict__ h2last, unsigned* __restrict__ bar,
    const float* __restrict__ Wih0, const float* __restrict__ Whh0,
    const float* __restrict__ bih0, const float* __restrict__ bhh0,
    const float* __restrict__ Wih1, const float* __restrict__ Whh1,
    const float* __restrict__ bih1, const float* __restrict__ bhh1,
    const float* __restrict__ Wih2, const float* __restrict__ Whh2,
    const float* __restrict__ bih2, const float* __restrict__ bhh2,
    const float* __restrict__ fcw, const float* __restrict__ fcb,
    float* __restrict__ out) {

    __shared__ short WA[64 * 64 * 16];     // 128 KB max (layer0 uses 36/64)
    __shared__ float redbuf[2 * 64 * 20];  // 10 KB
    __shared__ float fcred[256];

    const int l = blockIdx.x >> 6;
    const int tile = blockIdx.x & 63;
    const int sub = blockIdx.x & 7;

    if (l == 0)
        lstm_core<0, II, 36, 18, 72, 8>(tile, sub, xTq, ring0, ring1, h2last, bar,
                                        Wih0, Whh0, bih0, bhh0, WA, redbuf);
    else if (l == 1)
        lstm_core<1, HH, 64, 32, 128, 64>(tile, sub, xTq, ring1, ring2, h2last, bar,
                                          Wih1, Whh1, bih1, bhh1, WA, redbuf);
    else
        lstm_core<2, HH, 64, 32, 128, 64>(tile, sub, xTq, ring2, ring2, h2last, bar,
                                          Wih2, Whh2, bih2, bhh2, WA, redbuf);

    // final FC on h2[T-1]
    if (blockIdx.x == 0) {
        const int tid = threadIdx.x;
        const int b = tid & 63, kq = tid >> 6;
        float s = 0.f;
        const float* hp = h2last + (size_t)kq * 128 * 64 + b;
        const float* wp = fcw + kq * 128;
        #pragma unroll 8
        for (int k = 0; k < 128; ++k)
            s = fmaf(loadf_byp(hp + (size_t)k * 64), wp[k], s);
        fcred[tid] = s;
        __syncthreads();
        if (tid < 64)
            out[tid] = fcred[tid] + fcred[64 + tid] + fcred[128 + tid] + fcred[192 + tid] + fcb[0];
    }
}

extern "C" void kernel_launch(void* const* d_in, const int* in_sizes, int n_in,
                              void* d_out, int out_size, void* d_ws, size_t ws_size,
                              hipStream_t stream) {
    (void)in_sizes; (void)n_in; (void)out_size; (void)ws_size;

    const float* x    = (const float*)d_in[0];
    const float* Wih0 = (const float*)d_in[1];
    const float* Whh0 = (const float*)d_in[2];
    const float* bih0 = (const float*)d_in[3];
    const float* bhh0 = (const float*)d_in[4];
    const float* Wih1 = (const float*)d_in[5];
    const float* Whh1 = (const float*)d_in[6];
    const float* bih1 = (const float*)d_in[7];
    const float* bhh1 = (const float*)d_in[8];
    const float* Wih2 = (const float*)d_in[9];
    const float* Whh2 = (const float*)d_in[10];
    const float* bih2 = (const float*)d_in[11];
    const float* bhh2 = (const float*)d_in[12];
    const float* fcw  = (const float*)d_in[13];
    const float* fcb  = (const float*)d_in[14];

    char* ws = (char*)d_ws;
    unsigned* bar  = (unsigned*)ws;                        // 4 KB (tree barrier)
    char* ring0    = ws + 4096;
    char* ring1    = ring0 + 2 * 72 * 64 * 32;
    char* ring2    = ring1 + 2 * 128 * 64 * 32;
    float* h2last  = (float*)(ring2 + 2 * 128 * 64 * 32);
    char* xTq      = (char*)h2last + 512 * 64 * 4;

    hipMemsetAsync(bar, 0, 4096, stream);

    pack_x<<<TT, 256, 0, stream>>>(x, xTq);

    lstm_wavefront<<<NBLK, 256, 0, stream>>>(
        xTq, ring0, ring1, ring2, h2last, bar,
        Wih0, Whh0, bih0, bhh0,
        Wih1, Whh1, bih1, bhh1,
        Wih2, Whh2, bih2, bhh2,
        fcw, fcb, (float*)d_out);
}

// Round 7
// 6025.454 us; speedup vs baseline: 14.3598x; 1.0227x over previous
//
#include <hip/hip_runtime.h>
#include <math.h>

#define BB 64
#define TT 512
#define II 64
#define HH 512
#define NBLK 192

typedef __attribute__((ext_vector_type(8))) short bf16x8;
typedef __attribute__((ext_vector_type(16))) float f32x16;

__device__ __forceinline__ float sigmoidf_(float x) {
    return 1.0f / (1.0f + expf(-x));
}

__device__ __forceinline__ unsigned short f2bf(float f) {
    union { float f; unsigned u; } v; v.f = f;
    unsigned r = v.u + 0x7fffu + ((v.u >> 16) & 1u);   // RTNE
    return (unsigned short)(r >> 16);
}
__device__ __forceinline__ float bf2f(unsigned short s) {
    union { unsigned u; float f; } v; v.u = ((unsigned)s) << 16;
    return v.f;
}

// --- fence-free coherent primitives (agent scope; compiler-tracked vmcnt) ---
__device__ __forceinline__ bf16x8 load16_byp(const void* p) {
    union { unsigned long long u[2]; bf16x8 v; } r;
    r.u[0] = __hip_atomic_load((const unsigned long long*)p, __ATOMIC_RELAXED, __HIP_MEMORY_SCOPE_AGENT);
    r.u[1] = __hip_atomic_load((const unsigned long long*)((const char*)p + 8), __ATOMIC_RELAXED, __HIP_MEMORY_SCOPE_AGENT);
    return r.v;
}
__device__ __forceinline__ void store8_thru(void* p, unsigned long long u) {
    __hip_atomic_store((unsigned long long*)p, u, __ATOMIC_RELAXED, __HIP_MEMORY_SCOPE_AGENT);
}
__device__ __forceinline__ void storef_thru(float* p, float v) {
    __hip_atomic_store(p, v, __ATOMIC_RELAXED, __HIP_MEMORY_SCOPE_AGENT);
}
__device__ __forceinline__ float loadf_byp(const float* p) {
    return __hip_atomic_load(p, __ATOMIC_RELAXED, __HIP_MEMORY_SCOPE_AGENT);
}

// Per-layer 64-block barrier. bar words: cnt = bar[l*64], gen = bar[l*64+32].
// gen[l] == number of completed steps of layer l (monotonic within a launch;
// reset by the memset at the start of every kernel_launch / graph replay).
__device__ __forceinline__ void layer_barrier(unsigned* bar, int l) {
    __builtin_amdgcn_s_waitcnt(0);   // drain this wave's write-through stores
    __syncthreads();
    if (threadIdx.x == 0) {
        unsigned* cnt = bar + l * 64;
        unsigned* gen = bar + l * 64 + 32;
        const unsigned g = __hip_atomic_load(gen, __ATOMIC_RELAXED, __HIP_MEMORY_SCOPE_AGENT);
        const unsigned a = __hip_atomic_fetch_add(cnt, 1u, __ATOMIC_RELAXED, __HIP_MEMORY_SCOPE_AGENT);
        if (a == 63) {
            __hip_atomic_store(cnt, 0u, __ATOMIC_RELAXED, __HIP_MEMORY_SCOPE_AGENT);
            __hip_atomic_store(gen, g + 1u, __ATOMIC_RELAXED, __HIP_MEMORY_SCOPE_AGENT);
        } else {
            while (__hip_atomic_load(gen, __ATOMIC_RELAXED, __HIP_MEMORY_SCOPE_AGENT) == g)
                __builtin_amdgcn_s_sleep(1);
        }
    }
    __syncthreads();
}

__device__ __forceinline__ void poll_ge(unsigned* gen, unsigned tgt) {
    while (__hip_atomic_load(gen, __ATOMIC_RELAXED, __HIP_MEMORY_SCOPE_AGENT) < tgt)
        __builtin_amdgcn_s_sleep(1);
}

// x [B,T,I] -> xTq [t][grp][b][hi 16B | lo 16B], grp = i>>3
__global__ __launch_bounds__(256) void pack_x(const float* __restrict__ x,
                                              char* __restrict__ xTq) {
    const int t = blockIdx.x;
    const int b = threadIdx.x & 63;
    const int gq = threadIdx.x >> 6;
    #pragma unroll
    for (int gi = 0; gi < 2; ++gi) {
        const int g2 = gq + gi * 4;
        const float* src = x + ((size_t)b * TT + t) * II + g2 * 8;
        float w[8];
        *(float4*)&w[0] = *(const float4*)src;
        *(float4*)&w[4] = *(const float4*)(src + 4);
        bf16x8 hv, lv;
        #pragma unroll
        for (int j = 0; j < 8; ++j) {
            unsigned short h = f2bf(w[j]);
            hv[j] = (short)h;
            lv[j] = (short)f2bf(w[j] - bf2f(h));
        }
        char* dst = xTq + (((size_t)t * 8 + g2) * 64 + b) * 32;
        *(bf16x8*)dst = hv;
        *(bf16x8*)(dst + 16) = lv;
    }
}

// ---- software-pipelined B-panel (stage phase p+1 before consuming phase p) ----
// ksteps s < XEND come from xq (plain cached loads — layer0 xTq only);
// the rest from rb via bypass loads at (s-SH)*4096.
template<int S0, int S1, int XEND, int SH>
__device__ __forceinline__ void stage(const char* __restrict__ xq, const char* __restrict__ rb,
                                      bf16x8* __restrict__ bh, bf16x8* __restrict__ bl) {
    #pragma unroll
    for (int s = S0; s < S1; ++s) {
        if (s < XEND) {
            bh[s - S0] = *(const bf16x8*)(xq + (size_t)s * 4096);
            bl[s - S0] = *(const bf16x8*)(xq + (size_t)s * 4096 + 16);
        } else {
            bh[s - S0] = load16_byp(rb + (size_t)(s - SH) * 4096);
            bl[s - S0] = load16_byp(rb + (size_t)(s - SH) * 4096 + 16);
        }
    }
    __builtin_amdgcn_sched_barrier(0);   // all loads issued before following MFMAs
}

template<int S0, int S1, int NA>
__device__ __forceinline__ void consume(const short* __restrict__ wa_lane,
                                        bf16x8 (&bh)[NA], bf16x8 (&bl)[NA],
                                        f32x16& c0, f32x16& c1, f32x16& c2) {
    #pragma unroll
    for (int s = S0; s < S1; ++s) {
        bf16x8 ahi = *(const bf16x8*)(wa_lane + (size_t)s * 1024);
        bf16x8 alo = *(const bf16x8*)(wa_lane + (size_t)s * 1024 + 8);
        c0 = __builtin_amdgcn_mfma_f32_32x32x16_bf16(ahi, bh[s - S0], c0, 0, 0, 0);
        c1 = __builtin_amdgcn_mfma_f32_32x32x16_bf16(ahi, bl[s - S0], c1, 0, 0, 0);
        c2 = __builtin_amdgcn_mfma_f32_32x32x16_bf16(alo, bh[s - S0], c2, 0, 0, 0);
    }
}

template<int A, int B, int S1, int XEND, int SH, int PH, int NA>
__device__ __forceinline__ void pipe_next(const char* __restrict__ xq, const char* __restrict__ rb,
                                          const short* __restrict__ wa_lane,
                                          bf16x8 (&bh)[NA], bf16x8 (&bl)[NA],
                                          f32x16& c0, f32x16& c1, f32x16& c2) {
    if constexpr (B >= S1) {
        consume<A, B>(wa_lane, bh, bl, c0, c1, c2);
    } else {
        constexpr int N2 = (S1 - B) < PH ? (S1 - B) : PH;
        bf16x8 bh2[N2], bl2[N2];
        stage<B, B + N2, XEND, SH>(xq, rb, bh2, bl2);
        consume<A, B>(wa_lane, bh, bl, c0, c1, c2);
        pipe_next<B, B + N2, S1, XEND, SH, PH>(xq, rb, wa_lane, bh2, bl2, c0, c1, c2);
    }
}

template<int S0, int S1, int XEND, int SH, int PH>
__device__ __forceinline__ void pipe(const char* __restrict__ xq, const char* __restrict__ rb,
                                     const short* __restrict__ wa_lane,
                                     f32x16& c0, f32x16& c1, f32x16& c2) {
    constexpr int N1 = (S1 - S0) < PH ? (S1 - S0) : PH;
    bf16x8 bh[N1], bl[N1];
    stage<S0, S0 + N1, XEND, SH>(xq, rb, bh, bl);
    pipe_next<S0, S0 + N1, S1, XEND, SH, PH>(xq, rb, wa_lane, bh, bl, c0, c1, c2);
}

// Pack this block's 32 gate-rows (hi/lo bf16) into LDS in MFMA A-fragment order.
template<int IN_DIM, int NKS>
__device__ void pack_weights(const float* __restrict__ Wih, const float* __restrict__ Whh,
                             int hbase, short* __restrict__ WA) {
    const int lane = threadIdx.x & 63;
    const int wq = threadIdx.x >> 6;
    const int m = lane & 31, lg = lane >> 5;
    const int grow = (m >> 3) * HH + hbase + (m & 7);
    const float* wi = Wih + (size_t)grow * IN_DIM;
    const float* wh = Whh + (size_t)grow * HH;
    for (int s = wq; s < NKS; s += 4) {
        const int k8 = s * 16 + lg * 8;
        const float* src = (k8 < IN_DIM) ? (wi + k8) : (wh + (k8 - IN_DIM));
        float w[8];
        *(float4*)&w[0] = *(const float4*)src;
        *(float4*)&w[4] = *(const float4*)(src + 4);
        bf16x8 hv, lv;
        #pragma unroll
        for (int j = 0; j < 8; ++j) {
            unsigned short h = f2bf(w[j]);
            hv[j] = (short)h;
            lv[j] = (short)f2bf(w[j] - bf2f(h));
        }
        short* dst = WA + ((size_t)s * 64 + lane) * 16;
        *(bf16x8*)dst = hv;
        *(bf16x8*)(dst + 8) = lv;
    }
}

// Buffers:
//  xsrc: LAYER0 -> xTq [t][8 grps][64][32];  LAYER1/2 -> xbuf_l [3 slots][64 grps][64][32]
//  xdst: LAYER<2 -> xbuf_{l+1} (slot t%3);   hbuf: [2 par][64 grps][64][32] own-layer h
template<int LAYER, int IN_DIM, int NKS, int KH, int SH>
__device__ void lstm_core(int tile,
                          const char* __restrict__ xsrc, char* __restrict__ xdst,
                          char* __restrict__ hbuf,
                          float* __restrict__ h2last, unsigned* __restrict__ bar,
                          const float* __restrict__ Wih, const float* __restrict__ Whh,
                          const float* __restrict__ bih, const float* __restrict__ bhh,
                          short* __restrict__ WA, float* __restrict__ redbuf) {
    const int tid = threadIdx.x;
    const int lane = tid & 63;
    const int wq = tid >> 6;
    const int ntile = wq & 1;
    const int khalf = wq >> 1;
    const int lg = lane >> 5;
    const int b = ntile * 32 + (lane & 31);
    const int hbase = tile * 8;

    pack_weights<IN_DIM, NKS>(Wih, Whh, hbase, WA);

    float bias_v[16];
    float cst[4] = {0.f, 0.f, 0.f, 0.f};
    if (khalf == 0) {
        #pragma unroll
        for (int g = 0; g < 4; ++g)
            #pragma unroll
            for (int j = 0; j < 4; ++j) {
                const int grow = g * HH + hbase + j + 4 * lg;
                bias_v[g * 4 + j] = bih[grow] + bhh[grow];
            }
    }
    __syncthreads();   // WA ready

    const short* wa_lane = WA + lane * 16;
    unsigned* const genp_prev = bar + (size_t)((LAYER > 0 ? LAYER - 1 : 0) * 64 + 32);
    unsigned* const genp_next = bar + (size_t)((LAYER < 2 ? LAYER + 1 : 2) * 64 + 32);
    const int xoff = lg * 2048 + b * 32;

    for (int t = 0; t < TT; ++t) {
        f32x16 c0 = {0,0,0,0,0,0,0,0,0,0,0,0,0,0,0,0};
        f32x16 c1 = c0, c2 = c0;
        const char* rb = hbuf + (size_t)(t & 1) * 131072 + xoff;   // h(t-1) parity

        if (khalf == 0) {
            if (LAYER < 2 && t >= 3) poll_ge(genp_next, (unsigned)(t - 2));  // x-slot reuse safety
            if (LAYER > 0) poll_ge(genp_prev, (unsigned)(t + 1));            // x(t) available
            if (LAYER == 0) {
                const char* xq = xsrc + (size_t)t * 16384 + xoff;
                if (t > 0) pipe<0, KH, 4, SH, 8>(xq, rb, wa_lane, c0, c1, c2);
                else       pipe<0, 4, 4, SH, 8>(xq, rb, wa_lane, c0, c1, c2);
            } else {
                const char* xb = xsrc + (size_t)(t % 3) * 131072 + xoff;
                pipe<0, KH, 0, 0, 8>(nullptr, xb, wa_lane, c0, c1, c2);      // bypass x loads
            }
        } else {
            if (t > 0) pipe<KH, NKS, 0, SH, 8>(nullptr, rb, wa_lane, c0, c1, c2);
        }

        f32x16 cs = c0 + c1 + c2;

        if (khalf == 1) {
            float* pw = &redbuf[((size_t)ntile * 64 + lane) * 20];
            #pragma unroll
            for (int q = 0; q < 4; ++q) {
                float4 v; v.x = cs[q*4+0]; v.y = cs[q*4+1]; v.z = cs[q*4+2]; v.w = cs[q*4+3];
                *(float4*)(pw + q * 4) = v;
            }
        }
        __syncthreads();
        if (khalf == 0) {
            const float* pr = &redbuf[((size_t)ntile * 64 + lane) * 20];
            float gate[16];
            #pragma unroll
            for (int r = 0; r < 16; ++r) gate[r] = cs[r] + pr[r] + bias_v[r];

            unsigned short his[4], los[4];
            #pragma unroll
            for (int j = 0; j < 4; ++j) {
                const float iv = sigmoidf_(gate[0 + j]);
                const float fv = sigmoidf_(gate[4 + j]);
                const float gv = tanhf(gate[8 + j]);
                const float ov = sigmoidf_(gate[12 + j]);
                cst[j] = fv * cst[j] + iv * gv;
                const float hv = ov * tanhf(cst[j]);
                his[j] = f2bf(hv);
                los[j] = f2bf(hv - bf2f(his[j]));
                if (LAYER == 2 && t == TT - 1)
                    storef_thru(h2last + (size_t)(hbase + j + 4 * lg) * 64 + b, hv);
            }
            unsigned long long hi2 = (unsigned long long)((unsigned)his[0] | ((unsigned)his[1] << 16))
                                   | ((unsigned long long)((unsigned)his[2] | ((unsigned)his[3] << 16)) << 32);
            unsigned long long lo2 = (unsigned long long)((unsigned)los[0] | ((unsigned)los[1] << 16))
                                   | ((unsigned long long)((unsigned)los[2] | ((unsigned)los[3] << 16)) << 32);

            // own-layer h(t) -> parity (t+1)&1, grp = tile
            char* d2 = hbuf + (size_t)((t + 1) & 1) * 131072 + (size_t)tile * 2048 + b * 32 + lg * 8;
            store8_thru(d2, hi2);
            store8_thru(d2 + 16, lo2);
            if (LAYER < 2) {
                // next layer's x(t) -> slot t%3, grp = tile
                char* d1 = xdst + (size_t)(t % 3) * 131072 + (size_t)tile * 2048 + b * 32 + lg * 8;
                store8_thru(d1, hi2);
                store8_thru(d1 + 16, lo2);
            }
        }
        layer_barrier(bar, LAYER);
    }
}

__global__ __launch_bounds__(256, 1) void lstm_wavefront(
    const char* __restrict__ xTq,
    char* __restrict__ xbuf1, char* __restrict__ xbuf2,
    char* __restrict__ hbuf0, char* __restrict__ hbuf1, char* __restrict__ hbuf2,
    float* __restrict__ h2last, unsigned* __restrict__ bar,
    const float* __restrict__ Wih0, const float* __restrict__ Whh0,
    const float* __restrict__ bih0, const float* __restrict__ bhh0,
    const float* __restrict__ Wih1, const float* __restrict__ Whh1,
    const float* __restrict__ bih1, const float* __restrict__ bhh1,
    const float* __restrict__ Wih2, const float* __restrict__ Whh2,
    const float* __restrict__ bih2, const float* __restrict__ bhh2,
    const float* __restrict__ fcw, const float* __restrict__ fcb,
    float* __restrict__ out) {

    __shared__ short WA[64 * 64 * 16];     // 128 KB
    __shared__ float redbuf[2 * 64 * 20];  // 10 KB
    __shared__ float fcred[256];

    const int l = blockIdx.x >> 6;
    const int tile = blockIdx.x & 63;

    if (l == 0)
        lstm_core<0, II, 36, 18, 4>(tile, xTq, xbuf1, hbuf0, h2last, bar,
                                    Wih0, Whh0, bih0, bhh0, WA, redbuf);
    else if (l == 1)
        lstm_core<1, HH, 64, 32, 32>(tile, xbuf1, xbuf2, hbuf1, h2last, bar,
                                     Wih1, Whh1, bih1, bhh1, WA, redbuf);
    else
        lstm_core<2, HH, 64, 32, 32>(tile, xbuf2, nullptr, hbuf2, h2last, bar,
                                     Wih2, Whh2, bih2, bhh2, WA, redbuf);

    // final FC on h2[T-1]: wait for layer 2 completion, then reduce
    if (blockIdx.x == 0) {
        poll_ge(bar + 2 * 64 + 32, (unsigned)TT);
        const int tid = threadIdx.x;
        const int b = tid & 63, kq = tid >> 6;
        float s = 0.f;
        const float* hp = h2last + (size_t)kq * 128 * 64 + b;
        const float* wp = fcw + kq * 128;
        #pragma unroll 8
        for (int k = 0; k < 128; ++k)
            s = fmaf(loadf_byp(hp + (size_t)k * 64), wp[k], s);
        fcred[tid] = s;
        __syncthreads();
        if (tid < 64)
            out[tid] = fcred[tid] + fcred[64 + tid] + fcred[128 + tid] + fcred[192 + tid] + fcb[0];
    }
}

extern "C" void kernel_launch(void* const* d_in, const int* in_sizes, int n_in,
                              void* d_out, int out_size, void* d_ws, size_t ws_size,
                              hipStream_t stream) {
    (void)in_sizes; (void)n_in; (void)out_size; (void)ws_size;

    const float* x    = (const float*)d_in[0];
    const float* Wih0 = (const float*)d_in[1];
    const float* Whh0 = (const float*)d_in[2];
    const float* bih0 = (const float*)d_in[3];
    const float* bhh0 = (const float*)d_in[4];
    const float* Wih1 = (const float*)d_in[5];
    const float* Whh1 = (const float*)d_in[6];
    const float* bih1 = (const float*)d_in[7];
    const float* bhh1 = (const float*)d_in[8];
    const float* Wih2 = (const float*)d_in[9];
    const float* Whh2 = (const float*)d_in[10];
    const float* bih2 = (const float*)d_in[11];
    const float* bhh2 = (const float*)d_in[12];
    const float* fcw  = (const float*)d_in[13];
    const float* fcb  = (const float*)d_in[14];

    char* ws = (char*)d_ws;
    unsigned* bar = (unsigned*)ws;                 // 4 KB (3 layer barriers + gens)
    char* xbuf1   = ws + 4096;                     // 3*64*64*32 = 384 KB
    char* xbuf2   = xbuf1 + 3 * 64 * 64 * 32;
    char* hbuf0   = xbuf2 + 3 * 64 * 64 * 32;      // 2*64*64*32 = 256 KB each
    char* hbuf1   = hbuf0 + 2 * 64 * 64 * 32;
    char* hbuf2   = hbuf1 + 2 * 64 * 64 * 32;
    float* h2last = (float*)(hbuf2 + 2 * 64 * 64 * 32);   // 128 KB
    char* xTq     = (char*)h2last + 512 * 64 * 4;  // 8 MB

    hipMemsetAsync(bar, 0, 4096, stream);

    pack_x<<<TT, 256, 0, stream>>>(x, xTq);

    lstm_wavefront<<<NBLK, 256, 0, stream>>>(
        xTq, xbuf1, xbuf2, hbuf0, hbuf1, hbuf2, h2last, bar,
        Wih0, Whh0, bih0, bhh0,
        Wih1, Whh1, bih1, bhh1,
        Wih2, Whh2, bih2, bhh2,
        fcw, fcb, (float*)d_out);
}